// Round 1
// baseline (202.340 us; speedup 1.0000x reference)
//
#include <hip/hip_runtime.h>
#include <stdint.h>

// Geometry: B=16, E=H=1024, H4=4096, K_total = E+H = 2048. All f32.
//
// ZERO-WORKSPACE experiment: the harness poisons the full 256 MiB workspace
// with ~40 us fillBuffer dispatches each iteration (rocprof: WRITE_SIZE =
// 262144 KB fills dominate the timed region; our kernels are each <40 us).
// This version uses NO workspace at all: one fused kernel, no split-K, so
// there is nothing for the harness to re-poison on our behalf.
//
// Grid: 256 blocks x 256 threads (1 block/CU). Block bl owns 4 h-columns
// j0..j0+3 across ALL 4 gates (16 W-columns), full K=2048.
// Column mapping is XCD-contiguous: blocks on the same XCD (bl & 7) cover a
// contiguous 128-column band, so the 8 blocks that share each 128B line of
// Wi/Wh are co-resident on the same L2 (no cross-XCD over-fetch from the
// 16B-per-row access granularity).
#define H4_ 4096
#define B_  16

__global__ __launch_bounds__(256) void k_fused2(
    const float* __restrict__ x, const float* __restrict__ h,
    const float* __restrict__ cin,
    const float* __restrict__ Wi, const float* __restrict__ Wh,
    const float* __restrict__ Wi_b, const float* __restrict__ Wh_b,
    float* __restrict__ out)
{
    __shared__ float a_lds[256][16];    // 16 KB: A chunk, [k_local][batch]
    __shared__ float red[16][16][16];   // 16 KB: [k-stripe][batch][g*4+c]
    __shared__ float gsum[16][16];      //  1 KB: [batch][g*4+c]

    const int bl = blockIdx.x;
    // XCD-contiguous columns: xcd = bl & 7 covers j in [xcd*128, xcd*128+128)
    const int j0 = (bl & 7) * 128 + (bl >> 3) * 4;
    const int t  = threadIdx.x;
    const int g  = t & 3;               // gate 0..3
    const int bq = (t >> 2) & 3;        // batch quad (4 batches each)
    const int ks = t >> 4;              // k-stripe 0..15 (16 rows per chunk)

    float acc[4][4];                    // [batch-in-quad][col]
    #pragma unroll
    for (int r = 0; r < 4; r++)
        #pragma unroll
        for (int c = 0; c < 4; c++) acc[r][c] = 0.f;

    for (int m = 0; m < 8; ++m) {
        const float* A  = (m < 4) ? x : h;   // [16][1024]
        const float* W  = (m < 4) ? Wi : Wh; // [1024][4096]
        const int    e0 = (m & 3) * 256;

        // stage A chunk -> LDS: a_lds[kl][b] = A[b][e0+kl]  (proven k1 idiom)
        {
            const int b = t & 15, kc = t >> 4;         // 16 k's per thread
            const float* src = A + b * 1024 + e0 + kc * 16;   // 64B aligned
            float4 v0 = *(const float4*)(src);
            float4 v1 = *(const float4*)(src + 4);
            float4 v2 = *(const float4*)(src + 8);
            float4 v3 = *(const float4*)(src + 12);
            const float vv[16] = { v0.x, v0.y, v0.z, v0.w, v1.x, v1.y, v1.z, v1.w,
                                   v2.x, v2.y, v2.z, v2.w, v3.x, v3.y, v3.z, v3.w };
            #pragma unroll
            for (int j = 0; j < 16; j++) a_lds[kc * 16 + j][b] = vv[j];
        }
        __syncthreads();

        // compute: this thread reads W[e0+ks*16+i][g*1024 + j0 .. +3]
        const float* wp = W + (size_t)e0 * H4_ + g * 1024 + j0;
        #pragma unroll
        for (int i = 0; i < 16; i++) {
            const int kl = ks * 16 + i;
            float4 w = *(const float4*)(wp + (size_t)kl * H4_);   // 16B
            float4 a = *(const float4*)&a_lds[kl][bq * 4];        // 4 batches
            acc[0][0] += a.x * w.x; acc[0][1] += a.x * w.y; acc[0][2] += a.x * w.z; acc[0][3] += a.x * w.w;
            acc[1][0] += a.y * w.x; acc[1][1] += a.y * w.y; acc[1][2] += a.y * w.z; acc[1][3] += a.y * w.w;
            acc[2][0] += a.z * w.x; acc[2][1] += a.z * w.y; acc[2][2] += a.z * w.z; acc[2][3] += a.z * w.w;
            acc[3][0] += a.w * w.x; acc[3][1] += a.w * w.y; acc[3][2] += a.w * w.z; acc[3][3] += a.w * w.w;
        }
        __syncthreads();                // before next chunk overwrites a_lds
    }

    // cross-stripe reduction over the 16 k-stripes
    #pragma unroll
    for (int r = 0; r < 4; r++)
        *(float4*)&red[ks][bq * 4 + r][g * 4] =
            make_float4(acc[r][0], acc[r][1], acc[r][2], acc[r][3]);
    __syncthreads();
    {
        const int b = t >> 4, c16 = t & 15;     // c16 = g*4 + c
        float s = 0.f;
        #pragma unroll
        for (int kk = 0; kk < 16; kk++) s += red[kk][b][c16];
        gsum[b][c16] = s;
    }
    __syncthreads();

    // activations + output for 16 batches x 4 columns
    if (t < 64) {
        const int b = t >> 2, jj = t & 3;
        const int j = j0 + jj;
        const float s0 = gsum[b][jj]      + Wi_b[j]        + Wh_b[j];
        const float s1 = gsum[b][4 + jj]  + Wi_b[1024 + j] + Wh_b[1024 + j];
        const float s2 = gsum[b][8 + jj]  + Wi_b[2048 + j] + Wh_b[2048 + j];
        const float s3 = gsum[b][12 + jj] + Wi_b[3072 + j] + Wh_b[3072 + j];
        const float ig = 1.f / (1.f + __expf(-s0));
        const float fg = 1.f / (1.f + __expf(-s1));
        const float gg = tanhf(s2);
        const float og = 1.f / (1.f + __expf(-s3));
        const float cv = cin[b * 1024 + j];
        const float cn = fg * cv + ig * gg;
        const float hn = og * tanhf(cn);
        out[b * 1024 + j]         = hn;     // h_new
        out[16384 + b * 1024 + j] = cn;     // c_new
    }
}

extern "C" void kernel_launch(void* const* d_in, const int* in_sizes, int n_in,
                              void* d_out, int out_size, void* d_ws, size_t ws_size,
                              hipStream_t stream) {
    (void)in_sizes; (void)n_in; (void)out_size; (void)d_ws; (void)ws_size;
    const float* x    = (const float*)d_in[0];
    const float* h    = (const float*)d_in[1];
    const float* c    = (const float*)d_in[2];
    // d_in[3] = context (dead: multiplied by 0 in reference)
    const float* Wi   = (const float*)d_in[4];
    const float* Wi_b = (const float*)d_in[5];
    const float* Wh   = (const float*)d_in[6];
    const float* Wh_b = (const float*)d_in[7];
    // d_in[8..11] = AZ_* (dead)

    k_fused2<<<256, 256, 0, stream>>>(x, h, c, Wi, Wh, Wi_b, Wh_b,
                                      (float*)d_out);
}

// Round 2
// 182.876 us; speedup vs baseline: 1.1064x; 1.1064x over previous
//
#include <hip/hip_runtime.h>
#include <stdint.h>

// Geometry: B=16, E=H=1024, H4=4096, K_total = E+H = 2048. All f32.
//
// Overhead model (round-0/1 evidence): the harness unconditionally poisons
// the 256 MiB workspace (~40 us fill) and adds ~110 us of resets/gaps each
// iteration regardless of whether we use d_ws. dur_us = ~156 us fixed + our
// kernel time. So: use the workspace freely; minimize kernel time only.
//
// k1: split-K GEMM, 1024 blocks (4/CU, 16 waves/CU). Block = (ct, s):
//   ct = col-tile (32 consecutive cols = one 128B line), s = K-chunk 0..7
//   (chunks 0..3 = Wi/x rows, 4..7 = Wh/h rows, 256 rows each).
// XCD alignment: s = blockIdx.x & 7, so XCD x (blocks bl%8==x) owns one
// 256-row K-slice of W across ALL columns = 4 MiB = exactly its private L2.
// Across bench iterations that slice stays L2-resident.
#define H4_ 4096
#define B_  16

// ---- K1: ifgo partials. part[s][b][j] f32.  grid = 1024 x 256 thr.
__global__ __launch_bounds__(256) void k1_gemm(
    const float* __restrict__ x, const float* __restrict__ h,
    const float* __restrict__ Wi, const float* __restrict__ Wh,
    float* __restrict__ part)
{
    __shared__ float a_lds[256][16];      // 16 KB: A chunk, [k_local][batch]
    __shared__ float red[8][16][32];      // 16 KB: [k-stripe][b][c]

    const int s  = blockIdx.x & 7;        // K-chunk == XCD (bl % 8 heuristic)
    const int ct = blockIdx.x >> 3;       // 0..127 col tile
    const int j0 = ct * 32;
    const int t  = threadIdx.x;
    const int c8 = t & 7;                 // col quad index (8 x 4 cols = 32)
    const int bq = (t >> 3) & 3;          // batch quad
    const int ks = t >> 5;                // k-stripe 0..7 (32 rows each)

    float acc[4][4];
    #pragma unroll
    for (int r = 0; r < 4; r++)
        #pragma unroll
        for (int c = 0; c < 4; c++) acc[r][c] = 0.f;

    const float* A  = (s < 4) ? x : h;    // [16][1024] f32
    const float* W  = (s < 4) ? Wi : Wh;  // [1024][4096] f32
    const int    e0 = (s & 3) * 256;

    // stage A chunk -> LDS: a_lds[kl][b] = A[b][e0+kl]  (zero-conflict idiom)
    {
        const int b = t & 15, kc = t >> 4;        // 16 k's per thread
        const float* src = A + b * 1024 + e0 + kc * 16;  // 64B aligned
        float4 v0 = *(const float4*)(src);
        float4 v1 = *(const float4*)(src + 4);
        float4 v2 = *(const float4*)(src + 8);
        float4 v3 = *(const float4*)(src + 12);
        const float vv[16] = { v0.x, v0.y, v0.z, v0.w, v1.x, v1.y, v1.z, v1.w,
                               v2.x, v2.y, v2.z, v2.w, v3.x, v3.y, v3.z, v3.w };
        #pragma unroll
        for (int j = 0; j < 16; j++) a_lds[kc * 16 + j][b] = vv[j];
    }
    __syncthreads();

    // compute: 32 rows per stripe; wave covers 2 rows x 128B contiguous cols
    const float* wp = W + (size_t)e0 * H4_ + j0 + c8 * 4;
    #pragma unroll 8
    for (int i = 0; i < 32; i++) {
        const int kl = ks * 32 + i;               // row e0+kl <= 1023
        float4 w = *(const float4*)(wp + (size_t)kl * H4_);  // 4 cols, 16B
        float4 a = *(const float4*)&a_lds[kl][bq * 4];       // 4 batches
        acc[0][0] += a.x * w.x; acc[0][1] += a.x * w.y; acc[0][2] += a.x * w.z; acc[0][3] += a.x * w.w;
        acc[1][0] += a.y * w.x; acc[1][1] += a.y * w.y; acc[1][2] += a.y * w.z; acc[1][3] += a.y * w.w;
        acc[2][0] += a.z * w.x; acc[2][1] += a.z * w.y; acc[2][2] += a.z * w.z; acc[2][3] += a.z * w.w;
        acc[3][0] += a.w * w.x; acc[3][1] += a.w * w.y; acc[3][2] += a.w * w.z; acc[3][3] += a.w * w.w;
    }

    // cross-stripe reduction (8 ks) — same zero-conflict pattern as round 0
    #pragma unroll
    for (int r = 0; r < 4; r++)
        *(float4*)&red[ks][bq * 4 + r][c8 * 4] =
            make_float4(acc[r][0], acc[r][1], acc[r][2], acc[r][3]);
    __syncthreads();
    {
        const int b = t >> 4, c = t & 15;   // each thread: cols c and c+16
        float s0 = 0.f, s1 = 0.f;
        #pragma unroll
        for (int kk = 0; kk < 8; kk++) {
            s0 += red[kk][b][c];
            s1 += red[kk][b][c + 16];
        }
        float* dst = part + ((size_t)s * B_ + b) * H4_ + j0;
        dst[c]      = s0;
        dst[c + 16] = s1;
    }
}

// ---- K2: sum 8 split partials + biases, activations. out = [h_new | c_new]
__global__ __launch_bounds__(256) void k2_act(
    const float* __restrict__ part, const float* __restrict__ c,
    const float* __restrict__ Wi_b, const float* __restrict__ Wh_b,
    float* __restrict__ out)
{
    const int tg = blockIdx.x * 256 + threadIdx.x;   // 0..16383
    const int b  = tg >> 10;
    const int j  = tg & 1023;

    float g4[4];
    #pragma unroll
    for (int g = 0; g < 4; g++) {
        const int col = g * 1024 + j;
        float acc = Wi_b[col] + Wh_b[col];
        #pragma unroll
        for (int ss = 0; ss < 8; ss++)
            acc += part[((size_t)ss * B_ + b) * H4_ + col];
        g4[g] = acc;
    }
    const float ig = 1.f / (1.f + __expf(-g4[0]));
    const float fg = 1.f / (1.f + __expf(-g4[1]));
    const float gg = tanhf(g4[2]);
    const float og = 1.f / (1.f + __expf(-g4[3]));
    const float cv = c[tg];
    const float cn = fg * cv + ig * gg;
    const float hn = og * tanhf(cn);
    out[tg]         = hn;
    out[16384 + tg] = cn;
}

// ---- Fallback: fully fused, zero workspace (round-1 kernel, known-correct).
__global__ __launch_bounds__(256) void k_fused2(
    const float* __restrict__ x, const float* __restrict__ h,
    const float* __restrict__ cin,
    const float* __restrict__ Wi, const float* __restrict__ Wh,
    const float* __restrict__ Wi_b, const float* __restrict__ Wh_b,
    float* __restrict__ out)
{
    __shared__ float a_lds[256][16];
    __shared__ float red[16][16][16];
    __shared__ float gsum[16][16];

    const int bl = blockIdx.x;
    const int j0 = (bl & 7) * 128 + (bl >> 3) * 4;
    const int t  = threadIdx.x;
    const int g  = t & 3;
    const int bq = (t >> 2) & 3;
    const int ks = t >> 4;

    float acc[4][4];
    #pragma unroll
    for (int r = 0; r < 4; r++)
        #pragma unroll
        for (int c = 0; c < 4; c++) acc[r][c] = 0.f;

    for (int m = 0; m < 8; ++m) {
        const float* A  = (m < 4) ? x : h;
        const float* W  = (m < 4) ? Wi : Wh;
        const int    e0 = (m & 3) * 256;
        {
            const int b = t & 15, kc = t >> 4;
            const float* src = A + b * 1024 + e0 + kc * 16;
            float4 v0 = *(const float4*)(src);
            float4 v1 = *(const float4*)(src + 4);
            float4 v2 = *(const float4*)(src + 8);
            float4 v3 = *(const float4*)(src + 12);
            const float vv[16] = { v0.x, v0.y, v0.z, v0.w, v1.x, v1.y, v1.z, v1.w,
                                   v2.x, v2.y, v2.z, v2.w, v3.x, v3.y, v3.z, v3.w };
            #pragma unroll
            for (int jj = 0; jj < 16; jj++) a_lds[kc * 16 + jj][b] = vv[jj];
        }
        __syncthreads();
        const float* wp = W + (size_t)e0 * H4_ + g * 1024 + j0;
        #pragma unroll 4
        for (int i = 0; i < 16; i++) {
            const int kl = ks * 16 + i;
            float4 w = *(const float4*)(wp + (size_t)kl * H4_);
            float4 a = *(const float4*)&a_lds[kl][bq * 4];
            acc[0][0] += a.x * w.x; acc[0][1] += a.x * w.y; acc[0][2] += a.x * w.z; acc[0][3] += a.x * w.w;
            acc[1][0] += a.y * w.x; acc[1][1] += a.y * w.y; acc[1][2] += a.y * w.z; acc[1][3] += a.y * w.w;
            acc[2][0] += a.z * w.x; acc[2][1] += a.z * w.y; acc[2][2] += a.z * w.z; acc[2][3] += a.z * w.w;
            acc[3][0] += a.w * w.x; acc[3][1] += a.w * w.y; acc[3][2] += a.w * w.z; acc[3][3] += a.w * w.w;
        }
        __syncthreads();
    }

    #pragma unroll
    for (int r = 0; r < 4; r++)
        *(float4*)&red[ks][bq * 4 + r][g * 4] =
            make_float4(acc[r][0], acc[r][1], acc[r][2], acc[r][3]);
    __syncthreads();
    {
        const int b = t >> 4, c16 = t & 15;
        float sum = 0.f;
        #pragma unroll
        for (int kk = 0; kk < 16; kk++) sum += red[kk][b][c16];
        gsum[b][c16] = sum;
    }
    __syncthreads();

    if (t < 64) {
        const int b = t >> 2, jj = t & 3;
        const int j = j0 + jj;
        const float s0 = gsum[b][jj]      + Wi_b[j]        + Wh_b[j];
        const float s1 = gsum[b][4 + jj]  + Wi_b[1024 + j] + Wh_b[1024 + j];
        const float s2 = gsum[b][8 + jj]  + Wi_b[2048 + j] + Wh_b[2048 + j];
        const float s3 = gsum[b][12 + jj] + Wi_b[3072 + j] + Wh_b[3072 + j];
        const float ig = 1.f / (1.f + __expf(-s0));
        const float fg = 1.f / (1.f + __expf(-s1));
        const float gg = tanhf(s2);
        const float og = 1.f / (1.f + __expf(-s3));
        const float cv = cin[b * 1024 + j];
        const float cn = fg * cv + ig * gg;
        const float hn = og * tanhf(cn);
        out[b * 1024 + j]         = hn;
        out[16384 + b * 1024 + j] = cn;
    }
}

extern "C" void kernel_launch(void* const* d_in, const int* in_sizes, int n_in,
                              void* d_out, int out_size, void* d_ws, size_t ws_size,
                              hipStream_t stream) {
    (void)in_sizes; (void)n_in; (void)out_size;
    const float* x    = (const float*)d_in[0];
    const float* h    = (const float*)d_in[1];
    const float* c    = (const float*)d_in[2];
    // d_in[3] = context (dead: multiplied by 0 in reference)
    const float* Wi   = (const float*)d_in[4];
    const float* Wi_b = (const float*)d_in[5];
    const float* Wh   = (const float*)d_in[6];
    const float* Wh_b = (const float*)d_in[7];
    // d_in[8..11] = AZ_* (dead)

    float* part = (float*)d_ws;
    float* out  = (float*)d_out;

    const size_t need = 8ull * B_ * H4_ * sizeof(float);   // 2 MB
    if (ws_size >= need) {
        k1_gemm<<<1024, 256, 0, stream>>>(x, h, Wi, Wh, part);
        k2_act<<<64, 256, 0, stream>>>(part, c, Wi_b, Wh_b, out);
    } else {
        k_fused2<<<64 * 4, 256, 0, stream>>>(x, h, c, Wi, Wh, Wi_b, Wh_b, out);
    }
}